// Round 1
// baseline (404.835 us; speedup 1.0000x reference)
//
#include <hip/hip_runtime.h>
#include <hip/hip_bf16.h>

// Output semantics: codes[i,j,k] = float(argmax_k(logits[clamp(q[i,j],-128,127)+128]))
// (hard + soft - stop_grad(soft) == hard broadcast in forward numerics).
// Gumbel noise input is never read.

#define N_LEVELS 256
#define THD_NEG (-128)

// Kernel 1: per-row argmax of the 256x256 logits table -> 256 floats in ws.
__global__ __launch_bounds__(256) void olm_argmax_table(
    const float* __restrict__ logits, float* __restrict__ table) {
    int r = threadIdx.x;  // one block of 256 threads
    const float* row = logits + (size_t)r * N_LEVELS;
    float best = row[0];
    int bi = 0;
#pragma unroll 8
    for (int k = 1; k < N_LEVELS; ++k) {
        float v = row[k];
        if (v > best) { best = v; bi = k; }  // strict > keeps FIRST max (jnp.argmax)
    }
    table[r] = (float)bi;
}

// Kernel 2: each 64-lane group writes one 256-float output row (float4/lane).
__global__ __launch_bounds__(256) void olm_write_codes(
    const int* __restrict__ q, const float* __restrict__ table,
    float* __restrict__ out, int nrows) {
    __shared__ float tab[N_LEVELS];
    tab[threadIdx.x] = table[threadIdx.x];
    __syncthreads();

    int gid  = blockIdx.x * blockDim.x + threadIdx.x;
    int lane = gid & 63;
    int row0 = gid >> 6;
    int row_stride = (gridDim.x * blockDim.x) >> 6;

    for (int row = row0; row < nrows; row += row_stride) {
        int qv = q[row];
        qv = min(127, max(-128, qv));
        float v = tab[qv - THD_NEG];
        float4 v4 = {v, v, v, v};
        reinterpret_cast<float4*>(out + (size_t)row * N_LEVELS)[lane] = v4;
    }
}

// Fallback (only if ws too small): compute table per-block in LDS, then write.
__global__ __launch_bounds__(256) void olm_write_codes_fused(
    const int* __restrict__ q, const float* __restrict__ logits,
    float* __restrict__ out, int nrows) {
    __shared__ float tab[N_LEVELS];
    {
        const float* row = logits + (size_t)threadIdx.x * N_LEVELS;
        float best = row[0];
        int bi = 0;
        for (int k = 1; k < N_LEVELS; ++k) {
            float v = row[k];
            if (v > best) { best = v; bi = k; }
        }
        tab[threadIdx.x] = (float)bi;
    }
    __syncthreads();

    int gid  = blockIdx.x * blockDim.x + threadIdx.x;
    int lane = gid & 63;
    int row0 = gid >> 6;
    int row_stride = (gridDim.x * blockDim.x) >> 6;

    for (int row = row0; row < nrows; row += row_stride) {
        int qv = q[row];
        qv = min(127, max(-128, qv));
        float v = tab[qv - THD_NEG];
        float4 v4 = {v, v, v, v};
        reinterpret_cast<float4*>(out + (size_t)row * N_LEVELS)[lane] = v4;
    }
}

extern "C" void kernel_launch(void* const* d_in, const int* in_sizes, int n_in,
                              void* d_out, int out_size, void* d_ws, size_t ws_size,
                              hipStream_t stream) {
    const int*   q      = (const int*)d_in[0];     // quantized_values, int32 [512,512]
    const float* logits = (const float*)d_in[1];   // encoding_logits, f32 [256,256]
    // d_in[2] (gumbel_noise) intentionally unused: soft - stop_grad(soft) == 0 in fwd.
    float* out = (float*)d_out;

    const int nrows = in_sizes[0];                 // 512*512 = 262144
    const int block = 256;
    // 4 rows per block; grid-stride over rows. Cap grid for scheduler headroom.
    int rows_per_block = block / 64;
    int blocks_needed = (nrows + rows_per_block - 1) / rows_per_block;
    int grid = blocks_needed < 4096 ? blocks_needed : 4096;

    if (ws_size >= N_LEVELS * sizeof(float)) {
        float* table = (float*)d_ws;
        olm_argmax_table<<<1, 256, 0, stream>>>(logits, table);
        olm_write_codes<<<grid, block, 0, stream>>>(q, table, out, nrows);
    } else {
        olm_write_codes_fused<<<grid, block, 0, stream>>>(q, logits, out, nrows);
    }
}

// Round 3
// 383.049 us; speedup vs baseline: 1.0569x; 1.0569x over previous
//
#include <hip/hip_runtime.h>
#include <hip/hip_bf16.h>

// codes[i,j,k] = float(argmax_k(logits[clamp(q[i,j],-128,127)+128]))
// (hard + soft - stop_grad(soft) == hard broadcast in forward numerics; gumbel unused)

#define NLV 256

typedef float f32x4 __attribute__((ext_vector_type(4)));  // native vector: OK for nontemporal builtin

// Kernel 1: one wave per logits row. float4 loads, shfl_xor argmax reduce
// (first-max tie-break = smaller index wins on equal value, matching jnp.argmax).
__global__ __launch_bounds__(256) void olm_table(
    const float* __restrict__ logits, float* __restrict__ table) {
    int wid  = (blockIdx.x * blockDim.x + threadIdx.x) >> 6;  // wave id == row
    int lane = threadIdx.x & 63;
    if (wid >= NLV) return;

    f32x4 v4 = reinterpret_cast<const f32x4*>(logits + (size_t)wid * NLV)[lane];
    float best = v4.x; int bi = lane * 4;
    if (v4.y > best) { best = v4.y; bi = lane * 4 + 1; }
    if (v4.z > best) { best = v4.z; bi = lane * 4 + 2; }
    if (v4.w > best) { best = v4.w; bi = lane * 4 + 3; }

    for (int off = 32; off > 0; off >>= 1) {
        float ob = __shfl_xor(best, off, 64);
        int   oi = __shfl_xor(bi,   off, 64);
        if (ob > best || (ob == best && oi < bi)) { best = ob; bi = oi; }
    }
    if (lane == 0) table[wid] = (float)bi;
}

// Kernel 2: each wave owns a 64-row chunk. q loaded coalesced (1 int/lane),
// value for row r fetched via shfl, one nontemporal 16B store per lane per row
// (64 lanes x 16B = one contiguous 1 KiB output row).
__global__ __launch_bounds__(256) void olm_write(
    const int* __restrict__ q, const float* __restrict__ table,
    float* __restrict__ out, int nrows) {
    __shared__ float tab[NLV];
    tab[threadIdx.x] = table[threadIdx.x];  // blockDim.x == 256 == NLV
    __syncthreads();

    int lane = threadIdx.x & 63;
    int wid  = (blockIdx.x * blockDim.x + threadIdx.x) >> 6;
    int base = wid * 64;
    if (base >= nrows) return;
    int n = nrows - base; if (n > 64) n = 64;

    int qi = base + (lane < n ? lane : n - 1);
    int qv = q[qi];
    qv = min(127, max(-128, qv)) + 128;
    float myv = tab[qv];

    f32x4* orow = reinterpret_cast<f32x4*>(out + (size_t)base * NLV) + lane;
#pragma unroll 4
    for (int r = 0; r < n; ++r) {
        float v = __shfl(myv, r, 64);
        f32x4 v4 = {v, v, v, v};
        __builtin_nontemporal_store(v4, orow);
        orow += NLV / 4;  // next output row
    }
}

extern "C" void kernel_launch(void* const* d_in, const int* in_sizes, int n_in,
                              void* d_out, int out_size, void* d_ws, size_t ws_size,
                              hipStream_t stream) {
    const int*   q      = (const int*)d_in[0];    // [512,512] int32
    const float* logits = (const float*)d_in[1];  // [256,256] f32
    // d_in[2] (gumbel_noise) unused: soft - stop_grad(soft) == 0 in forward.
    float* out   = (float*)d_out;
    float* table = (float*)d_ws;                  // 256 floats of scratch

    const int nrows = in_sizes[0];                // 262144

    // table: 256 waves -> 64 blocks of 256
    olm_table<<<(NLV * 64 + 255) / 256, 256, 0, stream>>>(logits, table);

    // write: one wave per 64-row chunk
    int waves  = (nrows + 63) / 64;               // 4096
    int blocks = (waves * 64 + 255) / 256;        // 1024
    olm_write<<<blocks, 256, 0, stream>>>(q, table, out, nrows);
}